// Round 1
// baseline (1098.975 us; speedup 1.0000x reference)
//
#include <hip/hip_runtime.h>
#include <hip/hip_bf16.h>
#include <cmath>

typedef __bf16 bf16;
typedef __attribute__((ext_vector_type(8))) __bf16 bf16x8;
typedef __attribute__((ext_vector_type(4))) float f32x4;
typedef unsigned int u32;
typedef unsigned short u16;

#define D_MODEL 2048
#define NH 16
#define DQ 128
#define DH 2048
#define DFFN 8192
#define DOUT 22528
#define BATCH 2
#define SEQ 2048
#define NROWS 4096

__device__ __forceinline__ void gload16(const void* g, void* l) {
    __builtin_amdgcn_global_load_lds((__attribute__((address_space(1))) const void*)g,
                                     (__attribute__((address_space(3))) void*)l, 16, 0, 0);
}

__device__ __forceinline__ float bf2f(u16 u) {
    union { u32 i; float f; } c; c.i = ((u32)u) << 16; return c.f;
}

// ---------------- fp32 -> bf16 conversion ----------------
__global__ __launch_bounds__(256) void cvt_f32_bf16(const float* __restrict__ in,
                                                    bf16* __restrict__ out) {
    size_t i = ((size_t)blockIdx.x * 256 + threadIdx.x) * 8;
    float4 a = *(const float4*)(in + i);
    float4 b = *(const float4*)(in + i + 4);
    bf16x8 o;
    o[0]=(bf16)a.x; o[1]=(bf16)a.y; o[2]=(bf16)a.z; o[3]=(bf16)a.w;
    o[4]=(bf16)b.x; o[5]=(bf16)b.y; o[6]=(bf16)b.z; o[7]=(bf16)b.w;
    *(bf16x8*)(out + i) = o;
}

// ---------------- RMSNorm (fp32 in -> bf16 out) ----------------
__global__ __launch_bounds__(256) void rmsnorm_k(const float* __restrict__ x,
                                                 const float* __restrict__ g,
                                                 bf16* __restrict__ out) {
    __shared__ float red[4];
    const int row = blockIdx.x;
    const int t = threadIdx.x;
    const float* xr = x + (size_t)row * D_MODEL;
    float4 v0 = *(const float4*)(xr + t*8);
    float4 v1 = *(const float4*)(xr + t*8 + 4);
    float ss = v0.x*v0.x + v0.y*v0.y + v0.z*v0.z + v0.w*v0.w
             + v1.x*v1.x + v1.y*v1.y + v1.z*v1.z + v1.w*v1.w;
    #pragma unroll
    for (int m = 32; m >= 1; m >>= 1) ss += __shfl_xor(ss, m);
    if ((t & 63) == 0) red[t >> 6] = ss;
    __syncthreads();
    float tot = red[0] + red[1] + red[2] + red[3];
    float norm = sqrtf(tot) * 0.022097086912079608f;   // * D^-0.5
    float inv = 1.0f / fmaxf(norm, 1e-8f);
    float4 g0 = *(const float4*)(g + t*8);
    float4 g1 = *(const float4*)(g + t*8 + 4);
    bf16x8 o;
    o[0]=(bf16)(v0.x*inv*g0.x); o[1]=(bf16)(v0.y*inv*g0.y);
    o[2]=(bf16)(v0.z*inv*g0.z); o[3]=(bf16)(v0.w*inv*g0.w);
    o[4]=(bf16)(v1.x*inv*g1.x); o[5]=(bf16)(v1.y*inv*g1.y);
    o[6]=(bf16)(v1.z*inv*g1.z); o[7]=(bf16)(v1.w*inv*g1.w);
    *(bf16x8*)(out + (size_t)row * D_MODEL + t*8) = o;
}

// ---------------- BT GEMM: C[M,N] = A[M,K] * B[N,K]^T  (m97 structure) ----------------
// MODE 0: outb[m,n] = bf16(acc + bias[n])
// MODE 1: outf[m,n] = addsrc[m,n] + acc
template<int MODE>
__global__ __launch_bounds__(256) void gemm_bt(
    const bf16* __restrict__ A, const bf16* __restrict__ B,
    int M, int N, int K,
    const float* __restrict__ bias, bf16* __restrict__ outb,
    const float* __restrict__ addsrc, float* __restrict__ outf)
{
    __shared__ bf16 As[128][32];
    __shared__ bf16 Bs[128][32];
    const int tid = threadIdx.x;
    const int wid = tid >> 6, lane = tid & 63;
    const int la = lane & 15, hi = lane >> 4;
    const int m0 = blockIdx.y * 128, n0 = blockIdx.x * 128;
    const int wr = (wid >> 1) * 64, wc = (wid & 1) * 64;
    f32x4 acc[4][4] = {};
    const int idx0 = tid, idx1 = 256 + tid;
    const int r0 = idx0 >> 2, c0 = (idx0 & 3) << 3;
    const int r1 = idx1 >> 2, c1 = (idx1 & 3) << 3;
    const bf16* Ap0 = A + (size_t)(m0 + r0) * K + c0;
    const bf16* Ap1 = A + (size_t)(m0 + r1) * K + c1;
    const bf16* Bp0 = B + (size_t)(n0 + r0) * K + c0;
    const bf16* Bp1 = B + (size_t)(n0 + r1) * K + c1;
    char* asb = (char*)As + wid * 1024;
    char* bsb = (char*)Bs + wid * 1024;

    for (int k0 = 0; k0 < K; k0 += 32) {
        __syncthreads();
        gload16(Ap0 + k0, asb);
        gload16(Ap1 + k0, asb + 4096);
        gload16(Bp0 + k0, bsb);
        gload16(Bp1 + k0, bsb + 4096);
        __syncthreads();
        bf16x8 af[4], bfr[4];
        #pragma unroll
        for (int m = 0; m < 4; ++m) af[m] = *(const bf16x8*)&As[wr + m*16 + la][hi*8];
        #pragma unroll
        for (int n = 0; n < 4; ++n) bfr[n] = *(const bf16x8*)&Bs[wc + n*16 + la][hi*8];
        #pragma unroll
        for (int m = 0; m < 4; ++m)
            #pragma unroll
            for (int n = 0; n < 4; ++n)
                acc[m][n] = __builtin_amdgcn_mfma_f32_16x16x32_bf16(af[m], bfr[n], acc[m][n], 0, 0, 0);
    }

    #pragma unroll
    for (int m = 0; m < 4; ++m) {
        const int row = m0 + wr + m*16 + hi*4;
        #pragma unroll
        for (int n = 0; n < 4; ++n) {
            const int col = n0 + wc + n*16 + la;
            if (MODE == 0) {
                const float bv = bias[col];
                #pragma unroll
                for (int r = 0; r < 4; ++r)
                    outb[(size_t)(row + r) * N + col] = (bf16)(acc[m][n][r] + bv);
            } else {
                #pragma unroll
                for (int r = 0; r < 4; ++r) {
                    const size_t off = (size_t)(row + r) * N + col;
                    outf[off] = addsrc[off] + acc[m][n][r];
                }
            }
        }
    }
}

// ---------------- RoPE table ----------------
__global__ __launch_bounds__(256) void rope_table(float* __restrict__ ctab,
                                                  float* __restrict__ stab) {
    int idx = blockIdx.x * 256 + threadIdx.x;     // l*64 + i
    int l = idx >> 6, i = idx & 63;
    float inv = powf(10000.0f, -(float)i / 64.0f);
    float ang = (float)l * inv;
    float s, c;
    sincosf(ang, &s, &c);
    ctab[idx] = c; stab[idx] = s;
}

__device__ __forceinline__ u32 rope_pair(u32 u, float c, float s) {
    float t1 = bf2f((u16)(u & 0xffff));
    float t2 = bf2f((u16)(u >> 16));
    float r1 = t1 * c - t2 * s;
    float r2 = t1 * s + t2 * c;
    bf16 b1 = (bf16)r1, b2 = (bf16)r2;
    return (u32)__builtin_bit_cast(u16, b1) | ((u32)__builtin_bit_cast(u16, b2) << 16);
}

// ---------------- q/k rope + reshape to [B,H,L,128] ----------------
__global__ __launch_bounds__(256) void rope_qk(const bf16* __restrict__ h,
                                               const float* __restrict__ ctab,
                                               const float* __restrict__ stab,
                                               bf16* __restrict__ qb, bf16* __restrict__ kb) {
    int idx = blockIdx.x * 256 + threadIdx.x;     // (((b*2048+l)*16 + hh)*64 + i)
    int i  = idx & 63;
    int hh = (idx >> 6) & 15;
    int l  = (idx >> 10) & 2047;
    int b  = idx >> 21;
    size_t hrow = (size_t)(b * SEQ + l) * DOUT;
    float c = ctab[l*64 + i], s = stab[l*64 + i];
    u32 uq = *(const u32*)(h + hrow + hh*DQ + 2*i);
    u32 uk = *(const u32*)(h + hrow + DH + hh*DQ + 2*i);
    size_t orow = ((size_t)(b*NH + hh) * SEQ + l) * DQ + 2*i;
    *(u32*)(qb + orow) = rope_pair(uq, c, s);
    *(u32*)(kb + orow) = rope_pair(uk, c, s);
}

// ---------------- V transpose: h_bf16 v-section -> vt [B,H,128,L] ----------------
__global__ __launch_bounds__(256) void v_transpose(const bf16* __restrict__ h,
                                                   bf16* __restrict__ vt) {
    __shared__ u32 lds[64][68];
    const int lt = blockIdx.x, bh = blockIdx.y;
    const int b = bh >> 4, hh = bh & 15;
    const int t = threadIdx.x;
    const bf16* src = h + (size_t)(b * SEQ + lt * 64) * DOUT + 2*DH + hh * DQ;
    #pragma unroll
    for (int i = 0; i < 4; ++i) {
        int j = i*256 + t;
        int l = j >> 4, ch = j & 15;
        uint4 v = *(const uint4*)(src + (size_t)l * DOUT + ch*8);
        *(uint4*)&lds[l][ch*4] = v;
    }
    __syncthreads();
    bf16* dst = vt + (size_t)bh * DQ * SEQ + lt * 64;
    #pragma unroll
    for (int i = 0; i < 4; ++i) {
        int j = i*256 + t;
        int d = j >> 3, lc = j & 7;
        u32 out[4];
        #pragma unroll
        for (int m = 0; m < 4; ++m) {
            u32 a0 = lds[lc*8 + 2*m][d >> 1];
            u32 a1 = lds[lc*8 + 2*m + 1][d >> 1];
            u16 s0 = (d & 1) ? (u16)(a0 >> 16) : (u16)(a0 & 0xffff);
            u16 s1 = (d & 1) ? (u16)(a1 >> 16) : (u16)(a1 & 0xffff);
            out[m] = (u32)s0 | ((u32)s1 << 16);
        }
        *(uint4*)(dst + (size_t)d * SEQ + lc*8) = *(uint4*)out;
    }
}

// ---------------- SwiGLU: ag = a * silu(b) ----------------
__global__ __launch_bounds__(256) void silu_k(const bf16* __restrict__ h,
                                              bf16* __restrict__ ag) {
    size_t idx = ((size_t)blockIdx.x * 256 + threadIdx.x) * 8;
    int r = (int)(idx >> 13);
    int f = (int)(idx & 8191);
    const bf16* hr = h + (size_t)r * DOUT + 3*DH;
    bf16x8 va = *(const bf16x8*)(hr + f);
    bf16x8 vb = *(const bf16x8*)(hr + DFFN + f);
    bf16x8 o;
    #pragma unroll
    for (int j = 0; j < 8; ++j) {
        float a = (float)va[j];
        float b = (float)vb[j];
        float sil = b / (1.0f + __expf(-b));
        o[j] = (bf16)(a * sil);
    }
    *(bf16x8*)(ag + idx) = o;
}

// ---------------- causal flash attention ----------------
// Q,K: [B*H, L, 128] (roped); Vt: [B*H, 128, L]; O: [B, L, H*128] bf16
__global__ __launch_bounds__(256) void attn_fa(const bf16* __restrict__ Q,
                                               const bf16* __restrict__ Kb,
                                               const bf16* __restrict__ Vt,
                                               bf16* __restrict__ O) {
    __shared__ bf16 Ks[64][128];
    __shared__ bf16 Vts[128][64];
    __shared__ bf16 Ps[4][16][64];
    const int qt = blockIdx.x, bh = blockIdx.y;
    const int b = bh >> 4, hh = bh & 15;
    const int tid = threadIdx.x, wid = tid >> 6, lane = tid & 63;
    const int la = lane & 15, hi = lane >> 4;
    const bf16* Qp = Q + (size_t)bh * SEQ * DQ;
    const bf16* Kp = Kb + (size_t)bh * SEQ * DQ;
    const bf16* Vp = Vt + (size_t)bh * DQ * SEQ;
    const int q0w = qt * 64 + wid * 16;

    bf16x8 qf[4];
    #pragma unroll
    for (int s = 0; s < 4; ++s)
        qf[s] = *(const bf16x8*)(Qp + (size_t)(q0w + la) * DQ + s*32 + hi*8);

    f32x4 acc_o[8] = {};
    float m_run[4] = {-1e30f, -1e30f, -1e30f, -1e30f};
    float l_run[4] = {0.f, 0.f, 0.f, 0.f};
    const float scale = 0.08838834764831845f;

    const int nk = qt + 1;
    for (int kt = 0; kt < nk; ++kt) {
        const int k0 = kt * 64;
        __syncthreads();
        #pragma unroll
        for (int i = 0; i < 4; ++i) {
            int j = i*256 + tid;
            int kr = j >> 4, jg = j & 15;               // K tile: row, 16B granule
            gload16(Kp + (size_t)(k0 + kr) * DQ + ((jg ^ (kr & 7)) << 3),
                    (char*)Ks + i*4096 + wid*1024);
            int d = j >> 3, vg = j & 7;                 // Vt tile: row d, granule
            gload16(Vp + (size_t)d * SEQ + k0 + ((vg ^ (d & 7)) << 3),
                    (char*)Vts + i*4096 + wid*1024);
        }
        __syncthreads();

        f32x4 sacc[4] = {};
        #pragma unroll
        for (int g = 0; g < 4; ++g) {
            const int krow = g*16 + la;
            #pragma unroll
            for (int s = 0; s < 4; ++s) {
                bf16x8 kf = *(const bf16x8*)((const char*)Ks + krow*256 + (((s*4 + hi) ^ (la & 7)) << 4));
                sacc[g] = __builtin_amdgcn_mfma_f32_16x16x32_bf16(qf[s], kf, sacc[g], 0, 0, 0);
            }
        }

        float mnew[4];
        #pragma unroll
        for (int r = 0; r < 4; ++r) mnew[r] = m_run[r];
        #pragma unroll
        for (int g = 0; g < 4; ++g)
            #pragma unroll
            for (int r = 0; r < 4; ++r) {
                float sv = sacc[g][r] * scale;
                int qi = q0w + hi*4 + r;
                int ki = k0 + g*16 + la;
                sv = (ki <= qi) ? sv : -1e30f;
                sacc[g][r] = sv;
                mnew[r] = fmaxf(mnew[r], sv);
            }
        #pragma unroll
        for (int r = 0; r < 4; ++r) {
            float v = mnew[r];
            v = fmaxf(v, __shfl_xor(v, 1));
            v = fmaxf(v, __shfl_xor(v, 2));
            v = fmaxf(v, __shfl_xor(v, 4));
            v = fmaxf(v, __shfl_xor(v, 8));
            mnew[r] = v;
        }
        float resc[4], lsum[4];
        #pragma unroll
        for (int r = 0; r < 4; ++r) {
            resc[r] = __expf(m_run[r] - mnew[r]);
            m_run[r] = mnew[r];
            lsum[r] = 0.f;
        }
        #pragma unroll
        for (int g = 0; g < 4; ++g)
            #pragma unroll
            for (int r = 0; r < 4; ++r) {
                float p = __expf(sacc[g][r] - mnew[r]);
                sacc[g][r] = p;
                lsum[r] += p;
            }
        #pragma unroll
        for (int r = 0; r < 4; ++r) {
            float v = lsum[r];
            v += __shfl_xor(v, 1); v += __shfl_xor(v, 2);
            v += __shfl_xor(v, 4); v += __shfl_xor(v, 8);
            l_run[r] = l_run[r] * resc[r] + v;
        }
        // P -> LDS (swizzled), rescale O
        #pragma unroll
        for (int g = 0; g < 4; ++g)
            #pragma unroll
            for (int r = 0; r < 4; ++r) {
                int prow = hi*4 + r;
                int pcol = (g*16 + la) ^ ((prow & 7) << 3);
                Ps[wid][prow][pcol] = (bf16)sacc[g][r];
            }
        #pragma unroll
        for (int n = 0; n < 8; ++n)
            #pragma unroll
            for (int r = 0; r < 4; ++r) acc_o[n][r] *= resc[r];
        // PV
        #pragma unroll
        for (int kk = 0; kk < 2; ++kk) {
            bf16x8 pf = *(const bf16x8*)((const char*)&Ps[wid][0][0] + la*128 +
                                         (((kk*32 + hi*8) ^ ((la & 7) << 3)) << 1));
            #pragma unroll
            for (int n = 0; n < 8; ++n) {
                const int vrow = n*16 + la;
                bf16x8 vf = *(const bf16x8*)((const char*)Vts + vrow*128 + (((kk*4 + hi) ^ (la & 7)) << 4));
                acc_o[n] = __builtin_amdgcn_mfma_f32_16x16x32_bf16(pf, vf, acc_o[n], 0, 0, 0);
            }
        }
    }

    bf16* Op = O + (size_t)b * SEQ * DH + (size_t)hh * DQ;
    #pragma unroll
    for (int r = 0; r < 4; ++r) {
        int qi = q0w + hi*4 + r;
        float invl = 1.0f / l_run[r];
        #pragma unroll
        for (int n = 0; n < 8; ++n)
            Op[(size_t)qi * DH + n*16 + la] = (bf16)(acc_o[n][r] * invl);
    }
}

// ---------------- launch ----------------
extern "C" void kernel_launch(void* const* d_in, const int* in_sizes, int n_in,
                              void* d_out, int out_size, void* d_ws, size_t ws_size,
                              hipStream_t stream) {
    const float* x       = (const float*)d_in[0];
    const float* g       = (const float*)d_in[1];
    const float* W_dense = (const float*)d_in[2];
    const float* b_dense = (const float*)d_in[3];
    const float* W_attn  = (const float*)d_in[4];
    const float* W_ffn   = (const float*)d_in[5];
    float* out = (float*)d_out;

    char* ws = (char*)d_ws;
    bf16* normed  = (bf16*)(ws + 0);                    // 16.8 MB (reused as attn_buf)
    bf16* Wd_b    = (bf16*)(ws + 16777216);             // 92.3 MB (reused as q/k/vt)
    bf16* Wa_b    = (bf16*)(ws + 109051904);            // 8.4 MB
    bf16* Wf_b    = (bf16*)(ws + 117440512);            // 33.6 MB
    bf16* h_b     = (bf16*)(ws + 150994944);            // 184.5 MB
    bf16* ag_b    = (bf16*)(ws + 335544320);            // 67.1 MB
    float* ctab   = (float*)(ws + 402653184);           // 0.5 MB
    float* stab   = (float*)(ws + 403177472);           // 0.5 MB
    // aliases (safe by launch ordering):
    bf16* q_b  = (bf16*)(ws + 16777216);                // over Wd after dense GEMM
    bf16* k_b  = (bf16*)(ws + 16777216 + 16777216);
    bf16* vt_b = (bf16*)(ws + 16777216 + 33554432);
    bf16* attn_b = normed;                              // over normed after dense GEMM

    // 1-3: weight conversions
    cvt_f32_bf16<<<46137344/2048, 256, 0, stream>>>(W_dense, Wd_b);
    cvt_f32_bf16<<<4194304/2048, 256, 0, stream>>>(W_attn, Wa_b);
    cvt_f32_bf16<<<16777216/2048, 256, 0, stream>>>(W_ffn, Wf_b);
    // 4: rmsnorm
    rmsnorm_k<<<NROWS, 256, 0, stream>>>(x, g, normed);
    // 5: dense GEMM -> h (bf16, +bias)
    {
        dim3 grid(DOUT/128, NROWS/128);
        gemm_bt<0><<<grid, 256, 0, stream>>>(normed, Wd_b, NROWS, DOUT, D_MODEL,
                                             b_dense, h_b, nullptr, nullptr);
    }
    // 6: rope table
    rope_table<<<SEQ*64/256, 256, 0, stream>>>(ctab, stab);
    // 7: rope q/k + reshape
    rope_qk<<<4194304/256, 256, 0, stream>>>(h_b, ctab, stab, q_b, k_b);
    // 8: v transpose
    {
        dim3 grid(SEQ/64, BATCH*NH);
        v_transpose<<<grid, 256, 0, stream>>>(h_b, vt_b);
    }
    // 9: swiglu
    silu_k<<<(size_t)NROWS*DFFN/8/256, 256, 0, stream>>>(h_b, ag_b);
    // 10: attention
    {
        dim3 grid(SEQ/64, BATCH*NH);
        attn_fa<<<grid, 256, 0, stream>>>(q_b, k_b, vt_b, attn_b);
    }
    // 11: attn_out GEMM + residual(x) -> out
    {
        dim3 grid(D_MODEL/128, NROWS/128);
        gemm_bt<1><<<grid, 256, 0, stream>>>(attn_b, Wa_b, NROWS, D_MODEL, DH,
                                             nullptr, nullptr, x, out);
    }
    // 12: ffn_out GEMM accumulate -> out
    {
        dim3 grid(D_MODEL/128, NROWS/128);
        gemm_bt<1><<<grid, 256, 0, stream>>>(ag_b, Wf_b, NROWS, D_MODEL, DFFN,
                                             nullptr, nullptr, out, out);
    }
}

// Round 2
// 969.769 us; speedup vs baseline: 1.1332x; 1.1332x over previous
//
#include <hip/hip_runtime.h>
#include <hip/hip_bf16.h>
#include <cmath>

typedef __bf16 bf16;
typedef __attribute__((ext_vector_type(8))) __bf16 bf16x8;
typedef __attribute__((ext_vector_type(4))) float f32x4;
typedef unsigned int u32;
typedef unsigned short u16;

#define D_MODEL 2048
#define NH 16
#define DQ 128
#define DH 2048
#define DFFN 8192
#define DOUT 22528
#define BATCH 2
#define SEQ 2048
#define NROWS 4096

__device__ __forceinline__ void gload16(const void* g, void* l) {
    __builtin_amdgcn_global_load_lds((__attribute__((address_space(1))) const void*)g,
                                     (__attribute__((address_space(3))) void*)l, 16, 0, 0);
}

__device__ __forceinline__ float bf2f(u16 u) {
    union { u32 i; float f; } c; c.i = ((u32)u) << 16; return c.f;
}

// ---------------- fp32 -> bf16 conversion ----------------
__global__ __launch_bounds__(256) void cvt_f32_bf16(const float* __restrict__ in,
                                                    bf16* __restrict__ out) {
    size_t i = ((size_t)blockIdx.x * 256 + threadIdx.x) * 8;
    float4 a = *(const float4*)(in + i);
    float4 b = *(const float4*)(in + i + 4);
    bf16x8 o;
    o[0]=(bf16)a.x; o[1]=(bf16)a.y; o[2]=(bf16)a.z; o[3]=(bf16)a.w;
    o[4]=(bf16)b.x; o[5]=(bf16)b.y; o[6]=(bf16)b.z; o[7]=(bf16)b.w;
    *(bf16x8*)(out + i) = o;
}

// ---------------- RMSNorm (fp32 in -> bf16 out) ----------------
__global__ __launch_bounds__(256) void rmsnorm_k(const float* __restrict__ x,
                                                 const float* __restrict__ g,
                                                 bf16* __restrict__ out) {
    __shared__ float red[4];
    const int row = blockIdx.x;
    const int t = threadIdx.x;
    const float* xr = x + (size_t)row * D_MODEL;
    float4 v0 = *(const float4*)(xr + t*8);
    float4 v1 = *(const float4*)(xr + t*8 + 4);
    float ss = v0.x*v0.x + v0.y*v0.y + v0.z*v0.z + v0.w*v0.w
             + v1.x*v1.x + v1.y*v1.y + v1.z*v1.z + v1.w*v1.w;
    #pragma unroll
    for (int m = 32; m >= 1; m >>= 1) ss += __shfl_xor(ss, m);
    if ((t & 63) == 0) red[t >> 6] = ss;
    __syncthreads();
    float tot = red[0] + red[1] + red[2] + red[3];
    float norm = sqrtf(tot) * 0.022097086912079608f;   // * D^-0.5
    float inv = 1.0f / fmaxf(norm, 1e-8f);
    float4 g0 = *(const float4*)(g + t*8);
    float4 g1 = *(const float4*)(g + t*8 + 4);
    bf16x8 o;
    o[0]=(bf16)(v0.x*inv*g0.x); o[1]=(bf16)(v0.y*inv*g0.y);
    o[2]=(bf16)(v0.z*inv*g0.z); o[3]=(bf16)(v0.w*inv*g0.w);
    o[4]=(bf16)(v1.x*inv*g1.x); o[5]=(bf16)(v1.y*inv*g1.y);
    o[6]=(bf16)(v1.z*inv*g1.z); o[7]=(bf16)(v1.w*inv*g1.w);
    *(bf16x8*)(out + (size_t)row * D_MODEL + t*8) = o;
}

// ============ 256x256 pipelined BT GEMM: C[M,N] = A[M,K] * B[N,K]^T ============
// 8 waves (512 thr), BK=64, dbuf 128KB LDS, counted vmcnt(8), T2 swizzle, T5.
// MODE 0: outb[m,n] = bf16(acc + bias[n])
template<int MODE>
__global__ __launch_bounds__(512, 2) void gemm256(
    const bf16* __restrict__ A, const bf16* __restrict__ B,
    int M, int N, int K, int nbx,
    const float* __restrict__ bias, bf16* __restrict__ outb,
    const float* __restrict__ addsrc, float* __restrict__ outf)
{
    __shared__ char smem[131072];          // [2 buf][A 32KB | B 32KB]
    const int tid = threadIdx.x;
    const int wid = tid >> 6, lane = tid & 63;
    const int la = lane & 15, hi = lane >> 4;
    const int wm = wid >> 2, wn = wid & 3;

    // T1: bijective XCD swizzle (gridDim.x % 8 == 0 for all our shapes)
    const int nwg = gridDim.x;
    const int cpx = nwg >> 3;
    const int bI = blockIdx.x;
    const int wg = (bI & 7) * cpx + (bI >> 3);
    const int bm = wg / nbx, bn = wg % nbx;
    const size_t m0 = (size_t)bm * 256, n0 = (size_t)bn * 256;

    // staging addressing: per gload line c (0..3), wave stages LDS rows
    // [c*64 + wid*8, +8), granule = lane&7; source granule = (lane&7) ^ (row&7)
    const int lr = lane >> 3, lg = lane & 7;
    const int sg = lg ^ lr;                // row&7 == lr (wid*8, c*64 are mult of 8)
    const bf16* Asrc = A + (m0 + wid*8 + lr) * (size_t)K + sg*8;
    const bf16* Bsrc = B + (n0 + wid*8 + lr) * (size_t)K + sg*8;
    char* const myA = smem + wid*1024;
    char* const myB = smem + 32768 + wid*1024;

    // read addressing: phys granule = (kk*4 + hi) ^ (row&7), row&7 == la&7
    const int pg0 = (hi ^ (la & 7)) << 4;
    const int pg1 = ((4 + hi) ^ (la & 7)) << 4;

    f32x4 acc[8][4] = {};
    const int NT = K >> 6;

    // prologue: stage tile 0 -> buf0
    #pragma unroll
    for (int c = 0; c < 4; ++c) gload16(Asrc + (size_t)(c*64)*K, myA + c*8192);
    #pragma unroll
    for (int c = 0; c < 4; ++c) gload16(Bsrc + (size_t)(c*64)*K, myB + c*8192);

    for (int t = 0; t < NT; ++t) {
        const int buf = t & 1;
        // stage tile t+1 into buf^1 (freed by group t-1's end barrier)
        if (t + 1 < NT) {
            const size_t k0 = (size_t)(t + 1) << 6;
            const int bo = (buf ^ 1) << 16;
            #pragma unroll
            for (int c = 0; c < 4; ++c) gload16(Asrc + (size_t)(c*64)*K + k0, myA + bo + c*8192);
            #pragma unroll
            for (int c = 0; c < 4; ++c) gload16(Bsrc + (size_t)(c*64)*K + k0, myB + bo + c*8192);
            asm volatile("s_waitcnt vmcnt(8)" ::: "memory");   // tile t landed (mine)
        } else {
            asm volatile("s_waitcnt vmcnt(0)" ::: "memory");
        }
        __builtin_amdgcn_s_barrier();                          // tile t landed (all waves)
        asm volatile("" ::: "memory");

        const char* Ab = smem + (buf << 16);
        const char* Bb = Ab + 32768;
        // B fragments for the whole K-group (8 x ds_read_b128)
        bf16x8 bfr[4][2];
        #pragma unroll
        for (int n = 0; n < 4; ++n) {
            const char* p = Bb + (wn*64 + n*16 + la) * 128;
            bfr[n][0] = *(const bf16x8*)(p + pg0);
            bfr[n][1] = *(const bf16x8*)(p + pg1);
        }
        #pragma unroll
        for (int qd = 0; qd < 4; ++qd) {
            bf16x8 af[2][2];
            #pragma unroll
            for (int mm = 0; mm < 2; ++mm) {
                const char* p = Ab + (wm*128 + (qd*2 + mm)*16 + la) * 128;
                af[mm][0] = *(const bf16x8*)(p + pg0);
                af[mm][1] = *(const bf16x8*)(p + pg1);
            }
            __builtin_amdgcn_s_setprio(1);
            #pragma unroll
            for (int mm = 0; mm < 2; ++mm)
                #pragma unroll
                for (int n = 0; n < 4; ++n) {
                    acc[qd*2+mm][n] = __builtin_amdgcn_mfma_f32_16x16x32_bf16(af[mm][0], bfr[n][0], acc[qd*2+mm][n], 0, 0, 0);
                    acc[qd*2+mm][n] = __builtin_amdgcn_mfma_f32_16x16x32_bf16(af[mm][1], bfr[n][1], acc[qd*2+mm][n], 0, 0, 0);
                }
            __builtin_amdgcn_s_setprio(0);
        }
        __builtin_amdgcn_s_barrier();                          // all reads of buf done
        asm volatile("" ::: "memory");                         // before next stage into it
    }

    #pragma unroll
    for (int mf = 0; mf < 8; ++mf) {
        const size_t row = m0 + wm*128 + mf*16 + hi*4;
        #pragma unroll
        for (int nf = 0; nf < 4; ++nf) {
            const size_t col = n0 + wn*64 + nf*16 + la;
            if (MODE == 0) {
                const float bv = bias[col];
                #pragma unroll
                for (int r = 0; r < 4; ++r)
                    outb[(row + r) * N + col] = (bf16)(acc[mf][nf][r] + bv);
            } else {
                #pragma unroll
                for (int r = 0; r < 4; ++r) {
                    const size_t off = (row + r) * N + col;
                    outf[off] = addsrc[off] + acc[mf][nf][r];
                }
            }
        }
    }
}

// ---------------- 128x128 BT GEMM (m97 structure) for the small GEMMs ----------------
template<int MODE>
__global__ __launch_bounds__(256) void gemm_bt(
    const bf16* __restrict__ A, const bf16* __restrict__ B,
    int M, int N, int K,
    const float* __restrict__ bias, bf16* __restrict__ outb,
    const float* __restrict__ addsrc, float* __restrict__ outf)
{
    __shared__ bf16 As[128][32];
    __shared__ bf16 Bs[128][32];
    const int tid = threadIdx.x;
    const int wid = tid >> 6, lane = tid & 63;
    const int la = lane & 15, hi = lane >> 4;
    const int m0 = blockIdx.y * 128, n0 = blockIdx.x * 128;
    const int wr = (wid >> 1) * 64, wc = (wid & 1) * 64;
    f32x4 acc[4][4] = {};
    const int idx0 = tid, idx1 = 256 + tid;
    const int r0 = idx0 >> 2, c0 = (idx0 & 3) << 3;
    const int r1 = idx1 >> 2, c1 = (idx1 & 3) << 3;
    const bf16* Ap0 = A + (size_t)(m0 + r0) * K + c0;
    const bf16* Ap1 = A + (size_t)(m0 + r1) * K + c1;
    const bf16* Bp0 = B + (size_t)(n0 + r0) * K + c0;
    const bf16* Bp1 = B + (size_t)(n0 + r1) * K + c1;
    char* asb = (char*)As + wid * 1024;
    char* bsb = (char*)Bs + wid * 1024;

    for (int k0 = 0; k0 < K; k0 += 32) {
        __syncthreads();
        gload16(Ap0 + k0, asb);
        gload16(Ap1 + k0, asb + 4096);
        gload16(Bp0 + k0, bsb);
        gload16(Bp1 + k0, bsb + 4096);
        __syncthreads();
        bf16x8 af[4], bfr[4];
        #pragma unroll
        for (int m = 0; m < 4; ++m) af[m] = *(const bf16x8*)&As[wr + m*16 + la][hi*8];
        #pragma unroll
        for (int n = 0; n < 4; ++n) bfr[n] = *(const bf16x8*)&Bs[wc + n*16 + la][hi*8];
        #pragma unroll
        for (int m = 0; m < 4; ++m)
            #pragma unroll
            for (int n = 0; n < 4; ++n)
                acc[m][n] = __builtin_amdgcn_mfma_f32_16x16x32_bf16(af[m], bfr[n], acc[m][n], 0, 0, 0);
    }

    #pragma unroll
    for (int m = 0; m < 4; ++m) {
        const int row = m0 + wr + m*16 + hi*4;
        #pragma unroll
        for (int n = 0; n < 4; ++n) {
            const int col = n0 + wc + n*16 + la;
            if (MODE == 0) {
                const float bv = bias[col];
                #pragma unroll
                for (int r = 0; r < 4; ++r)
                    outb[(size_t)(row + r) * N + col] = (bf16)(acc[m][n][r] + bv);
            } else {
                #pragma unroll
                for (int r = 0; r < 4; ++r) {
                    const size_t off = (size_t)(row + r) * N + col;
                    outf[off] = addsrc[off] + acc[m][n][r];
                }
            }
        }
    }
}

// ---------------- RoPE table ----------------
__global__ __launch_bounds__(256) void rope_table(float* __restrict__ ctab,
                                                  float* __restrict__ stab) {
    int idx = blockIdx.x * 256 + threadIdx.x;     // l*64 + i
    int l = idx >> 6, i = idx & 63;
    float inv = powf(10000.0f, -(float)i / 64.0f);
    float ang = (float)l * inv;
    float s, c;
    sincosf(ang, &s, &c);
    ctab[idx] = c; stab[idx] = s;
}

__device__ __forceinline__ u32 rope_pair(u32 u, float c, float s) {
    float t1 = bf2f((u16)(u & 0xffff));
    float t2 = bf2f((u16)(u >> 16));
    float r1 = t1 * c - t2 * s;
    float r2 = t1 * s + t2 * c;
    bf16 b1 = (bf16)r1, b2 = (bf16)r2;
    return (u32)__builtin_bit_cast(u16, b1) | ((u32)__builtin_bit_cast(u16, b2) << 16);
}

// ---------------- q/k rope + reshape to [B,H,L,128] ----------------
__global__ __launch_bounds__(256) void rope_qk(const bf16* __restrict__ h,
                                               const float* __restrict__ ctab,
                                               const float* __restrict__ stab,
                                               bf16* __restrict__ qb, bf16* __restrict__ kb) {
    int idx = blockIdx.x * 256 + threadIdx.x;     // (((b*2048+l)*16 + hh)*64 + i)
    int i  = idx & 63;
    int hh = (idx >> 6) & 15;
    int l  = (idx >> 10) & 2047;
    int b  = idx >> 21;
    size_t hrow = (size_t)(b * SEQ + l) * DOUT;
    float c = ctab[l*64 + i], s = stab[l*64 + i];
    u32 uq = *(const u32*)(h + hrow + hh*DQ + 2*i);
    u32 uk = *(const u32*)(h + hrow + DH + hh*DQ + 2*i);
    size_t orow = ((size_t)(b*NH + hh) * SEQ + l) * DQ + 2*i;
    *(u32*)(qb + orow) = rope_pair(uq, c, s);
    *(u32*)(kb + orow) = rope_pair(uk, c, s);
}

// ---------------- V transpose: h_bf16 v-section -> vt [B,H,128,L] ----------------
__global__ __launch_bounds__(256) void v_transpose(const bf16* __restrict__ h,
                                                   bf16* __restrict__ vt) {
    __shared__ u32 lds[64][68];
    const int lt = blockIdx.x, bh = blockIdx.y;
    const int b = bh >> 4, hh = bh & 15;
    const int t = threadIdx.x;
    const bf16* src = h + (size_t)(b * SEQ + lt * 64) * DOUT + 2*DH + hh * DQ;
    #pragma unroll
    for (int i = 0; i < 4; ++i) {
        int j = i*256 + t;
        int l = j >> 4, ch = j & 15;
        uint4 v = *(const uint4*)(src + (size_t)l * DOUT + ch*8);
        *(uint4*)&lds[l][ch*4] = v;
    }
    __syncthreads();
    bf16* dst = vt + (size_t)bh * DQ * SEQ + lt * 64;
    #pragma unroll
    for (int i = 0; i < 4; ++i) {
        int j = i*256 + t;
        int d = j >> 3, lc = j & 7;
        u32 out[4];
        #pragma unroll
        for (int m = 0; m < 4; ++m) {
            u32 a0 = lds[lc*8 + 2*m][d >> 1];
            u32 a1 = lds[lc*8 + 2*m + 1][d >> 1];
            u16 s0 = (d & 1) ? (u16)(a0 >> 16) : (u16)(a0 & 0xffff);
            u16 s1 = (d & 1) ? (u16)(a1 >> 16) : (u16)(a1 & 0xffff);
            out[m] = (u32)s0 | ((u32)s1 << 16);
        }
        *(uint4*)(dst + (size_t)d * SEQ + lc*8) = *(uint4*)out;
    }
}

// ---------------- SwiGLU: ag = a * silu(b) ----------------
__global__ __launch_bounds__(256) void silu_k(const bf16* __restrict__ h,
                                              bf16* __restrict__ ag) {
    size_t idx = ((size_t)blockIdx.x * 256 + threadIdx.x) * 8;
    int r = (int)(idx >> 13);
    int f = (int)(idx & 8191);
    const bf16* hr = h + (size_t)r * DOUT + 3*DH;
    bf16x8 va = *(const bf16x8*)(hr + f);
    bf16x8 vb = *(const bf16x8*)(hr + DFFN + f);
    bf16x8 o;
    #pragma unroll
    for (int j = 0; j < 8; ++j) {
        float a = (float)va[j];
        float b = (float)vb[j];
        float sil = b / (1.0f + __expf(-b));
        o[j] = (bf16)(a * sil);
    }
    *(bf16x8*)(ag + idx) = o;
}

// ---------------- causal flash attention ----------------
__global__ __launch_bounds__(256) void attn_fa(const bf16* __restrict__ Q,
                                               const bf16* __restrict__ Kb,
                                               const bf16* __restrict__ Vt,
                                               bf16* __restrict__ O) {
    __shared__ bf16 Ks[64][128];
    __shared__ bf16 Vts[128][64];
    __shared__ bf16 Ps[4][16][64];
    const int qt = blockIdx.x, bh = blockIdx.y;
    const int b = bh >> 4, hh = bh & 15;
    const int tid = threadIdx.x, wid = tid >> 6, lane = tid & 63;
    const int la = lane & 15, hi = lane >> 4;
    const bf16* Qp = Q + (size_t)bh * SEQ * DQ;
    const bf16* Kp = Kb + (size_t)bh * SEQ * DQ;
    const bf16* Vp = Vt + (size_t)bh * DQ * SEQ;
    const int q0w = qt * 64 + wid * 16;

    bf16x8 qf[4];
    #pragma unroll
    for (int s = 0; s < 4; ++s)
        qf[s] = *(const bf16x8*)(Qp + (size_t)(q0w + la) * DQ + s*32 + hi*8);

    f32x4 acc_o[8] = {};
    float m_run[4] = {-1e30f, -1e30f, -1e30f, -1e30f};
    float l_run[4] = {0.f, 0.f, 0.f, 0.f};
    const float scale = 0.08838834764831845f;

    const int nk = qt + 1;
    for (int kt = 0; kt < nk; ++kt) {
        const int k0 = kt * 64;
        __syncthreads();
        #pragma unroll
        for (int i = 0; i < 4; ++i) {
            int j = i*256 + tid;
            int kr = j >> 4, jg = j & 15;               // K tile: row, 16B granule
            gload16(Kp + (size_t)(k0 + kr) * DQ + ((jg ^ (kr & 7)) << 3),
                    (char*)Ks + i*4096 + wid*1024);
            int d = j >> 3, vg = j & 7;                 // Vt tile: row d, granule
            gload16(Vp + (size_t)d * SEQ + k0 + ((vg ^ (d & 7)) << 3),
                    (char*)Vts + i*4096 + wid*1024);
        }
        __syncthreads();

        f32x4 sacc[4] = {};
        __builtin_amdgcn_s_setprio(1);
        #pragma unroll
        for (int g = 0; g < 4; ++g) {
            const int krow = g*16 + la;
            #pragma unroll
            for (int s = 0; s < 4; ++s) {
                bf16x8 kf = *(const bf16x8*)((const char*)Ks + krow*256 + (((s*4 + hi) ^ (la & 7)) << 4));
                sacc[g] = __builtin_amdgcn_mfma_f32_16x16x32_bf16(qf[s], kf, sacc[g], 0, 0, 0);
            }
        }
        __builtin_amdgcn_s_setprio(0);

        float mnew[4];
        #pragma unroll
        for (int r = 0; r < 4; ++r) mnew[r] = m_run[r];
        #pragma unroll
        for (int g = 0; g < 4; ++g)
            #pragma unroll
            for (int r = 0; r < 4; ++r) {
                float sv = sacc[g][r] * scale;
                int qi = q0w + hi*4 + r;
                int ki = k0 + g*16 + la;
                sv = (ki <= qi) ? sv : -1e30f;
                sacc[g][r] = sv;
                mnew[r] = fmaxf(mnew[r], sv);
            }
        #pragma unroll
        for (int r = 0; r < 4; ++r) {
            float v = mnew[r];
            v = fmaxf(v, __shfl_xor(v, 1));
            v = fmaxf(v, __shfl_xor(v, 2));
            v = fmaxf(v, __shfl_xor(v, 4));
            v = fmaxf(v, __shfl_xor(v, 8));
            mnew[r] = v;
        }
        float resc[4], lsum[4];
        #pragma unroll
        for (int r = 0; r < 4; ++r) {
            resc[r] = __expf(m_run[r] - mnew[r]);
            m_run[r] = mnew[r];
            lsum[r] = 0.f;
        }
        #pragma unroll
        for (int g = 0; g < 4; ++g)
            #pragma unroll
            for (int r = 0; r < 4; ++r) {
                float p = __expf(sacc[g][r] - mnew[r]);
                sacc[g][r] = p;
                lsum[r] += p;
            }
        #pragma unroll
        for (int r = 0; r < 4; ++r) {
            float v = lsum[r];
            v += __shfl_xor(v, 1); v += __shfl_xor(v, 2);
            v += __shfl_xor(v, 4); v += __shfl_xor(v, 8);
            l_run[r] = l_run[r] * resc[r] + v;
        }
        #pragma unroll
        for (int g = 0; g < 4; ++g)
            #pragma unroll
            for (int r = 0; r < 4; ++r) {
                int prow = hi*4 + r;
                int pcol = (g*16 + la) ^ ((prow & 7) << 3);
                Ps[wid][prow][pcol] = (bf16)sacc[g][r];
            }
        #pragma unroll
        for (int n = 0; n < 8; ++n)
            #pragma unroll
            for (int r = 0; r < 4; ++r) acc_o[n][r] *= resc[r];
        __builtin_amdgcn_s_setprio(1);
        #pragma unroll
        for (int kk = 0; kk < 2; ++kk) {
            bf16x8 pf = *(const bf16x8*)((const char*)&Ps[wid][0][0] + la*128 +
                                         (((kk*32 + hi*8) ^ ((la & 7) << 3)) << 1));
            #pragma unroll
            for (int n = 0; n < 8; ++n) {
                const int vrow = n*16 + la;
                bf16x8 vf = *(const bf16x8*)((const char*)Vts + vrow*128 + (((kk*4 + hi) ^ (la & 7)) << 4));
                acc_o[n] = __builtin_amdgcn_mfma_f32_16x16x32_bf16(pf, vf, acc_o[n], 0, 0, 0);
            }
        }
        __builtin_amdgcn_s_setprio(0);
    }

    bf16* Op = O + (size_t)b * SEQ * DH + (size_t)hh * DQ;
    #pragma unroll
    for (int r = 0; r < 4; ++r) {
        int qi = q0w + hi*4 + r;
        float invl = 1.0f / l_run[r];
        #pragma unroll
        for (int n = 0; n < 8; ++n)
            Op[(size_t)qi * DH + n*16 + la] = (bf16)(acc_o[n][r] * invl);
    }
}

// ---------------- launch ----------------
extern "C" void kernel_launch(void* const* d_in, const int* in_sizes, int n_in,
                              void* d_out, int out_size, void* d_ws, size_t ws_size,
                              hipStream_t stream) {
    const float* x       = (const float*)d_in[0];
    const float* g       = (const float*)d_in[1];
    const float* W_dense = (const float*)d_in[2];
    const float* b_dense = (const float*)d_in[3];
    const float* W_attn  = (const float*)d_in[4];
    const float* W_ffn   = (const float*)d_in[5];
    float* out = (float*)d_out;

    char* ws = (char*)d_ws;
    bf16* normed  = (bf16*)(ws + 0);                    // 16.8 MB (reused as attn_buf)
    bf16* Wd_b    = (bf16*)(ws + 16777216);             // 92.3 MB (reused as q/k/vt)
    bf16* Wa_b    = (bf16*)(ws + 109051904);            // 8.4 MB
    bf16* Wf_b    = (bf16*)(ws + 117440512);            // 33.6 MB
    bf16* h_b     = (bf16*)(ws + 150994944);            // 184.5 MB
    bf16* ag_b    = (bf16*)(ws + 335544320);            // 67.1 MB
    float* ctab   = (float*)(ws + 402653184);           // 0.5 MB
    float* stab   = (float*)(ws + 403177472);           // 0.5 MB
    bf16* q_b  = (bf16*)(ws + 16777216);
    bf16* k_b  = (bf16*)(ws + 16777216 + 16777216);
    bf16* vt_b = (bf16*)(ws + 16777216 + 33554432);
    bf16* attn_b = normed;

    cvt_f32_bf16<<<46137344/2048, 256, 0, stream>>>(W_dense, Wd_b);
    cvt_f32_bf16<<<4194304/2048, 256, 0, stream>>>(W_attn, Wa_b);
    cvt_f32_bf16<<<16777216/2048, 256, 0, stream>>>(W_ffn, Wf_b);
    rmsnorm_k<<<NROWS, 256, 0, stream>>>(x, g, normed);
    // dense GEMM -> h (bf16, +bias): 256^2 pipelined kernel
    {
        dim3 grid((NROWS/256) * (DOUT/256));            // 16*88 = 1408, %8==0
        gemm256<0><<<grid, 512, 0, stream>>>(normed, Wd_b, NROWS, DOUT, D_MODEL,
                                             DOUT/256, b_dense, h_b, nullptr, nullptr);
    }
    rope_table<<<SEQ*64/256, 256, 0, stream>>>(ctab, stab);
    rope_qk<<<4194304/256, 256, 0, stream>>>(h_b, ctab, stab, q_b, k_b);
    {
        dim3 grid(SEQ/64, BATCH*NH);
        v_transpose<<<grid, 256, 0, stream>>>(h_b, vt_b);
    }
    silu_k<<<(size_t)NROWS*DFFN/8/256, 256, 0, stream>>>(h_b, ag_b);
    {
        dim3 grid(SEQ/64, BATCH*NH);
        attn_fa<<<grid, 256, 0, stream>>>(q_b, k_b, vt_b, attn_b);
    }
    {
        dim3 grid(D_MODEL/128, NROWS/128);
        gemm_bt<1><<<grid, 256, 0, stream>>>(attn_b, Wa_b, NROWS, D_MODEL, DH,
                                             nullptr, nullptr, x, out);
    }
    {
        dim3 grid(D_MODEL/128, NROWS/128);
        gemm_bt<1><<<grid, 256, 0, stream>>>(ag_b, Wf_b, NROWS, D_MODEL, DFFN,
                                             nullptr, nullptr, out, out);
    }
}